// Round 20
// baseline (183.091 us; speedup 1.0000x reference)
//
#include <hip/hip_runtime.h>
#include <stdint.h>

// Problem constants (fixed by the reference)
#define NQ 2048
#define NK 4096
#define DFF 2048
#define SPLITS 8

using u16 = unsigned short;
typedef float f32x4 __attribute__((ext_vector_type(4)));
typedef short s16x8 __attribute__((ext_vector_type(8)));
typedef __attribute__((address_space(3))) void as3_void;
typedef __attribute__((address_space(1))) void as1_void;

__device__ __forceinline__ u16 f2h(float f) {           // fp32 -> fp16 bits (RNE)
  _Float16 h = (_Float16)f;
  return __builtin_bit_cast(u16, h);
}
__device__ __forceinline__ float h2f(u16 u) {
  return (float)__builtin_bit_cast(_Float16, u);
}
__device__ __forceinline__ void mfma16h(f32x4& d, s16x8 a, s16x8 b) {  // fp16
  asm volatile("v_mfma_f32_16x16x32_f16 %0, %1, %2, %0" : "+v"(d) : "v"(a), "v"(b));
}
// async global->LDS DMA, 16B/lane; LDS dest = wave-uniform base + lane*16.
__device__ __forceinline__ void gll16(const void* g, const void* l) {
  uint32_t off = (uint32_t)(uintptr_t)l;
  off = (uint32_t)__builtin_amdgcn_readfirstlane((int)off);
  __builtin_amdgcn_global_load_lds((const as1_void*)(uintptr_t)g,
                                   (as3_void*)(uintptr_t)off, 16, 0, 0);
}

// ---------------------------------------------------------------------------
// PREP: transpose+quantize tgt/mem (blocks 0..3071) + quantize all 7 weights
// (blocks 3072..4095) + int64-detect + zero Gp accumulator (blocks 4096..4863).
// Runs first in stream order every call -> Gp is freshly zeroed per replay.
// ---------------------------------------------------------------------------
__global__ __launch_bounds__(256) void prep_kernel(
    const float* __restrict__ TGT, u16* __restrict__ OT,
    const float* __restrict__ MEM, u16* __restrict__ OM,
    const float* __restrict__ S1, u16* __restrict__ H1, int n1,   // W1
    const float* __restrict__ S2, u16* __restrict__ H2, int n2,   // Wd
    const float* __restrict__ S3, u16* __restrict__ H3, int n3,   // W2
    const float* __restrict__ S4, u16* __restrict__ H4, int n4,   // Wq
    const float* __restrict__ S5, u16* __restrict__ H5, int n5,   // Wk
    const float* __restrict__ S6, u16* __restrict__ H6, int n6,   // Wv
    const float* __restrict__ S7, u16* __restrict__ H7, int n7,   // Wo
    const int* __restrict__ IP, int* __restrict__ flag,
    float* __restrict__ GpZero)
{
  const int bx = blockIdx.x;
  if (bx >= 4096) {
    // zero the 6144x128 fp32 atomic accumulator: 196608 float4 = 768 x 256
    float4* g4 = (float4*)GpZero;
    g4[(size_t)(bx - 4096) * 256 + threadIdx.x] = make_float4(0.f, 0.f, 0.f, 0.f);
    return;
  }
  if (bx < 3072) {
    // transpose+quantize: fp32 [n][i*3+c] -> fp16 [(n*3+c)][i]
    const float* X = (bx < 1024) ? TGT : MEM;
    u16* O = (bx < 1024) ? OT : OM;
    const int n0 = ((bx < 1024) ? bx : bx - 1024) * 2;
    for (int e = threadIdx.x; e < 768; e += 256) {
      const int nl = (e >= 384);
      const int r = e - nl * 384;           // c*128 + i
      const int c = r >> 7, i = r & 127;
      O[(size_t)(n0 + nl) * 384 + r] = f2h(X[(size_t)(n0 + nl) * 384 + i * 3 + c]);
    }
    return;
  }
  const int qbx = bx - 3072;                // 1024 quant blocks
  if (qbx == 0 && threadIdx.x == 0) {
    int f = 1;
    for (int j = 1; j < 128; j += 2) f &= (IP[j] == 0);
    *flag = f;
  }
  const int q1 = n1 >> 2, q2 = n2 >> 2, q3 = n3 >> 2, q4 = n4 >> 2;
  const int q5 = n5 >> 2, q6 = n6 >> 2, q7 = n7 >> 2;
  const int e1 = q1, e2 = e1 + q2, e3 = e2 + q3, e4 = e3 + q4;
  const int e5 = e4 + q5, e6 = e5 + q6, e7 = e6 + q7;
  int i = qbx * 256 + threadIdx.x;
  const int stride = 1024 * 256;
  for (; i < e7; i += stride) {
    const float* S;
    u16* H;
    int j = i;
    if (j < e1)      { S = S1; H = H1; }
    else if (j < e2) { S = S2; H = H2; j -= e1; }
    else if (j < e3) { S = S3; H = H3; j -= e2; }
    else if (j < e4) { S = S4; H = H4; j -= e3; }
    else if (j < e5) { S = S5; H = H5; j -= e4; }
    else if (j < e6) { S = S6; H = H6; j -= e5; }
    else             { S = S7; H = H7; j -= e6; }
    float4 v = ((const float4*)S)[j];
    ushort4 o;
    o.x = f2h(v.x); o.y = f2h(v.y); o.z = f2h(v.z); o.w = f2h(v.w);
    ((ushort4*)H)[j] = o;
  }
}

// ---------------------------------------------------------------------------
// Gathered multi-head attention, transposed fp16 operands.
// qT: [(n*3+c)][128] fp16. KV: [(m*3+c)][256] fp16 (cols 0-127 = K, 128-255 = V).
// Output aoutT: [(n*3+c)][128] fp16 (feature index = h*16+d).
// ---------------------------------------------------------------------------
__global__ __launch_bounds__(512) void attn_kernel(
    const u16* __restrict__ qT, const u16* __restrict__ KV,
    const int* __restrict__ IP, const int* __restrict__ KBC,
    const int* __restrict__ IPB, const int* __restrict__ FLAG,
    u16* __restrict__ aoutT)
{
  const int n = blockIdx.x;
  const int t = threadIdx.x;
  const int h = t >> 6, l = t & 63;
  __shared__ float qs[384];             // qs[c*128 + i]
  __shared__ float attn_s[8][64];
  __shared__ int gi_s[8][64];
  if (t < 384) qs[t] = h2f(qT[(size_t)n * 384 + t]);
  const int is64 = *FLAG;
  const long long* IP64 = (const long long*)IP;
  const long long* KBC64 = (const long long*)KBC;
  const long long* IPB64 = (const long long*)IPB;
  const int b = is64 ? (int)IPB64[n] : IPB[n];
  int ks0 = 0;
#pragma unroll
  for (int j = 0; j < 4; ++j) {
    int cnt = is64 ? (int)KBC64[j] : KBC[j];
    ks0 += (j < b) ? cnt : 0;  // exclusive cumsum
  }
  const int ip = is64 ? (int)IP64[(size_t)n * 64 + l] : IP[(size_t)n * 64 + l];
  const bool valid = ip >= 0;
  const int gi = ks0 + (valid ? ip : 0);
  __syncthreads();
  // scores: sum over c (3) x d (16): K at KV[gi*768 + c*256 + h*16 + d]
  const u16* kb = KV + (size_t)gi * 768 + h * 16;
  float s = 0.f;
#pragma unroll
  for (int c = 0; c < 3; ++c) {
    s16x8 k0 = *(const s16x8*)(kb + c * 256);
    s16x8 k1 = *(const s16x8*)(kb + c * 256 + 8);
#pragma unroll
    for (int e = 0; e < 8; ++e) {
      s = fmaf(h2f((u16)k0[e]), qs[c * 128 + h * 16 + e], s);
      s = fmaf(h2f((u16)k1[e]), qs[c * 128 + h * 16 + 8 + e], s);
    }
  }
  s *= 0.25f;  // 1/sqrt(hd)
  if (!valid) s = -1e9f;
  float m = s;
  for (int off = 32; off; off >>= 1) m = fmaxf(m, __shfl_xor(m, off));
  float e = __expf(s - m);
  float sum = e;
  for (int off = 32; off; off >>= 1) sum += __shfl_xor(sum, off);
  attn_s[h][l] = e / sum;
  gi_s[h][l] = gi;
  __syncthreads();
  if (l < 48) {
    const int c = l >> 4, d = l & 15;   // V at KV[gi*768 + c*256 + 128 + h*16+d]
    float acc = 0.f;
#pragma unroll 4
    for (int ll = 0; ll < 64; ++ll)
      acc = fmaf(attn_s[h][ll],
                 h2f(KV[(size_t)gi_s[h][ll] * 768 + c * 256 + 128 + h * 16 + d]), acc);
    aoutT[(size_t)n * 384 + c * 128 + h * 16 + d] = f2h(acc);
  }
}

// ---------------------------------------------------------------------------
// VN LayerNorm 1: h1 = VNLN(x + tgt2). X fp32 [n][i*3+c]; T2T fp32
// [(n*3+c)][128]. Writes fp32 [(n*3+c)][128] AND fp16 plane.
// ---------------------------------------------------------------------------
__global__ __launch_bounds__(128) void ln1_kernel(
    const float* __restrict__ X, const float* __restrict__ T2T,
    const float* __restrict__ G, const float* __restrict__ Bb,
    float* __restrict__ Hf, u16* __restrict__ Hh)
{
  const int n = blockIdx.x, i = threadIdx.x;
  const size_t b0 = (size_t)n * 384 + i * 3;
  const size_t h0 = (size_t)n * 384 + i;  // (n*3+c)*128 + i == n*384 + c*128 + i
  float v0 = X[b0 + 0] + T2T[h0 + 0];
  float v1 = X[b0 + 1] + T2T[h0 + 128];
  float v2 = X[b0 + 2] + T2T[h0 + 256];
  float nn = sqrtf(v0 * v0 + v1 * v1 + v2 * v2 + 1e-6f);
  float s1 = nn, s2 = nn * nn;
  for (int off = 32; off; off >>= 1) { s1 += __shfl_xor(s1, off); s2 += __shfl_xor(s2, off); }
  __shared__ float red[4];
  if ((i & 63) == 0) { red[(i >> 6) * 2] = s1; red[(i >> 6) * 2 + 1] = s2; }
  __syncthreads();
  float mu = (red[0] + red[2]) * (1.0f / 128.0f);
  float ms = (red[1] + red[3]) * (1.0f / 128.0f);
  float var = ms - mu * mu;
  float nnew = (nn - mu) * rsqrtf(var + 1e-5f) * G[i] + Bb[i];
  float sc = nnew / nn;
  float o0 = v0 * sc, o1 = v1 * sc, o2 = v2 * sc;
  Hf[h0 + 0]   = o0;
  Hf[h0 + 128] = o1;
  Hf[h0 + 256] = o2;
  Hh[h0 + 0]   = f2h(o0);
  Hh[h0 + 128] = f2h(o1);
  Hh[h0 + 256] = f2h(o2);
}

// ---------------------------------------------------------------------------
// VN LayerNorm 2: out = VNLN(h1 + Gp); fp32 in (single accumulated plane),
// fp32 out [n][i*3+c].
// ---------------------------------------------------------------------------
__global__ __launch_bounds__(128) void ln2_kernel(
    const float* __restrict__ Hf, const float* __restrict__ Gp,
    const float* __restrict__ G, const float* __restrict__ Bb, float* __restrict__ O)
{
  const int n = blockIdx.x, i = threadIdx.x;
  float v[3];
#pragma unroll
  for (int c = 0; c < 3; ++c) {
    const size_t idx = (size_t)n * 384 + c * 128 + i;
    v[c] = Hf[idx] + Gp[idx];
  }
  float nn = sqrtf(v[0] * v[0] + v[1] * v[1] + v[2] * v[2] + 1e-6f);
  float s1 = nn, s2 = nn * nn;
  for (int off = 32; off; off >>= 1) { s1 += __shfl_xor(s1, off); s2 += __shfl_xor(s2, off); }
  __shared__ float red[4];
  if ((i & 63) == 0) { red[(i >> 6) * 2] = s1; red[(i >> 6) * 2 + 1] = s2; }
  __syncthreads();
  float mu = (red[0] + red[2]) * (1.0f / 128.0f);
  float ms = (red[1] + red[3]) * (1.0f / 128.0f);
  float var = ms - mu * mu;
  float nnew = (nn - mu) * rsqrtf(var + 1e-5f) * G[i] + Bb[i];
  float sc = nnew / nn;
  const size_t o0 = (size_t)n * 384 + i * 3;
  O[o0 + 0] = v[0] * sc;
  O[o0 + 1] = v[1] * sc;
  O[o0 + 2] = v[2] * sc;
}

// ---------------------------------------------------------------------------
// VN-ReLU, vectorized x8, fp16, OUT-OF-PLACE (F,D -> P). No RMW anywhere.
// ---------------------------------------------------------------------------
__global__ __launch_bounds__(256) void vnrelu8_kernel(
    const u16* __restrict__ F, const u16* __restrict__ D, u16* __restrict__ P)
{
  const size_t idx = (size_t)blockIdx.x * 256 + threadIdx.x;  // one per 8 elems
  const size_t n = idx >> 8;              // DFF/8 = 256 groups per token
  const size_t oo = (idx & 255) << 3;
  const size_t base = n * 3 * DFF + oo;
  s16x8 f0 = *(const s16x8*)(F + base);
  s16x8 f1 = *(const s16x8*)(F + base + DFF);
  s16x8 f2 = *(const s16x8*)(F + base + 2 * DFF);
  s16x8 d0 = *(const s16x8*)(D + base);
  s16x8 d1 = *(const s16x8*)(D + base + DFF);
  s16x8 d2 = *(const s16x8*)(D + base + 2 * DFF);
  s16x8 r0, r1, r2;
#pragma unroll
  for (int e = 0; e < 8; ++e) {
    float a0 = h2f((u16)f0[e]), a1 = h2f((u16)f1[e]), a2 = h2f((u16)f2[e]);
    float b0 = h2f((u16)d0[e]), b1 = h2f((u16)d1[e]), b2 = h2f((u16)d2[e]);
    float dot = a0 * b0 + a1 * b1 + a2 * b2;
    float r = (dot < 0.0f) ? dot / (b0 * b0 + b1 * b1 + b2 * b2 + 1e-6f) : 0.0f;
    r0[e] = (short)f2h(a0 - r * b0);
    r1[e] = (short)f2h(a1 - r * b1);
    r2[e] = (short)f2h(a2 - r * b2);
  }
  *(s16x8*)(P + base) = r0;
  *(s16x8*)(P + base + DFF) = r1;
  *(s16x8*)(P + base + 2 * DFF) = r2;
}

// ---------------------------------------------------------------------------
// fp16 NT GEMM, phase-scheduled 256x256 tile (proven ~73 us @K=2048).
// BK=32, 8 waves (2Mx4N), per-wave 128x64 out (acc 8x4 frags).
// LDS 3-buffer ring (96 KiB), depth-2 gll16 prefetch. Wd GEMM only.
// ---------------------------------------------------------------------------
__global__ __launch_bounds__(512, 1) void gemm_f16_256(
    const u16* __restrict__ A, const u16* __restrict__ B,
    u16* __restrict__ C, int M, int N, int K)
{
  __shared__ __align__(16) u16 lds[3][2][16][64][8];  // 96 KiB ring
  const int tid = threadIdx.x;
  const int wave = tid >> 6, lane = tid & 63;
  const int bm = blockIdx.x, bn = blockIdx.y;
  const int NT = K >> 5;
  const int fr = lane & 15;          // row within 16-row fragment
  const int kg = (lane >> 4) << 3;   // k sub-offset 0/8/16/24
  const int wm = wave >> 2, wn = wave & 3;   // 2 x 4 wave grid
  f32x4 acc[8][4] = {};

  auto stageA = [&](int buf, int kt) {   // 2 gll16: A-frags {2w, 2w+1}
#pragma unroll
    for (int i = 0; i < 2; ++i) {
      const int f = wave * 2 + i;
      gll16(A + (size_t)(bm * 256 + f * 16 + fr) * K + (kt << 5) + kg,
            &lds[buf][0][f][0][0]);
    }
  };
  auto stageB = [&](int buf, int kt) {   // 2 gll16: B-frags {2w, 2w+1}
#pragma unroll
    for (int i = 0; i < 2; ++i) {
      const int f = wave * 2 + i;
      gll16(B + (size_t)(bn * 256 + f * 16 + fr) * K + (kt << 5) + kg,
            &lds[buf][1][f][0][0]);
    }
  };

  // prologue: tiles 0,1 in flight (8 loads/wave); retire tile 0, publish.
  stageA(0, 0); stageB(0, 0);
  stageA(1, 1); stageB(1, 1);
  asm volatile("s_waitcnt vmcnt(4)" ::: "memory");
  __builtin_amdgcn_s_barrier();
  __builtin_amdgcn_sched_barrier(0);

  s16x8 bf[4];
  for (int t = 0; t < NT; ++t) {
    const int cur = t % 3;
    const int nx2 = (t + 2) % 3;
    // ---- phase 0: a-half 0 + all b; stage A of tile t+2 ----
    s16x8 af[4];
#pragma unroll
    for (int i = 0; i < 4; ++i)
      af[i] = *(const s16x8*)(&lds[cur][0][wm * 8 + i][lane][0]);
#pragma unroll
    for (int j = 0; j < 4; ++j)
      bf[j] = *(const s16x8*)(&lds[cur][1][wn * 4 + j][lane][0]);
    if (t + 2 < NT) stageA(nx2, t + 2);
    __builtin_amdgcn_s_barrier();
    asm volatile("s_waitcnt lgkmcnt(0)" ::: "memory");
    __builtin_amdgcn_sched_barrier(0);
    __builtin_amdgcn_s_setprio(1);
#pragma unroll
    for (int i = 0; i < 4; ++i)
#pragma unroll
      for (int j = 0; j < 4; ++j) mfma16h(acc[i][j], af[i], bf[j]);
    __builtin_amdgcn_s_setprio(0);
    // ---- phase 1: a-half 1, b reused from registers; stage B of t+2 ----
#pragma unroll
    for (int i = 0; i < 4; ++i)
      af[i] = *(const s16x8*)(&lds[cur][0][wm * 8 + 4 + i][lane][0]);
    if (t + 2 < NT) stageB(nx2, t + 2);
    __builtin_amdgcn_s_barrier();
    asm volatile("s_waitcnt lgkmcnt(0)" ::: "memory");
    __builtin_amdgcn_sched_barrier(0);
    __builtin_amdgcn_s_setprio(1);
#pragma unroll
    for (int i = 0; i < 4; ++i)
#pragma unroll
      for (int j = 0; j < 4; ++j) mfma16h(acc[4 + i][j], af[i], bf[j]);
    __builtin_amdgcn_s_setprio(0);
    // ---- tile boundary: tile t+1 must be fully landed & published ----
    if (t + 1 < NT) {
      if (t + 2 < NT) {
        asm volatile("s_waitcnt vmcnt(4)" ::: "memory");  // retire t+1's 4, keep t+2's
      } else {
        asm volatile("s_waitcnt vmcnt(0)" ::: "memory");  // tail: nothing newer
      }
      __builtin_amdgcn_s_barrier();
      __builtin_amdgcn_sched_barrier(0);
    }
  }

  // epilogue: C/D frag layout col = lane&15, row = (lane>>4)*4 + reg
  const int r0 = bm * 256 + wm * 128 + (lane >> 4) * 4;
  const int c0 = bn * 256 + wn * 64 + (lane & 15);
#pragma unroll
  for (int ia = 0; ia < 8; ++ia)
#pragma unroll
    for (int jb = 0; jb < 4; ++jb)
#pragma unroll
      for (int r = 0; r < 4; ++r)
        C[(size_t)(r0 + ia * 16 + r) * N + (c0 + jb * 16)] = f2h(acc[ia][jb][r]);
}

// ---------------------------------------------------------------------------
// fp16 NT GEMM: 128x128 tile, BK=32, 4 waves. Register-staged LDS, 2 barriers
// per K-step (replay-proven dynamics). Used for all small-K GEMMs.
// MODE 0: fp16 C. MODE 1: fp32 partials at (float*)C + bz*M*N (split-K on z).
// MODE 2: fp32 atomicAdd into single (float*)C plane (split-K on z; C must be
//         pre-zeroed by an earlier kernel in stream order).
// ---------------------------------------------------------------------------
template <int MODE>
__global__ __launch_bounds__(256) void gemm_f16(
    const u16* __restrict__ A, const u16* __restrict__ B,
    void* __restrict__ Cout, int M, int N, int K)
{
  __shared__ __align__(16) u16 lds[2][8][64][8];  // 16 KiB: A,B
  const int tid = threadIdx.x;
  const int wave = tid >> 6, lane = tid & 63;
  const int bm = blockIdx.x, bn = blockIdx.y, bz = blockIdx.z;
  const int kChunk = K / (int)gridDim.z;
  const int k0 = bz * kChunk;
  const int nt = kChunk >> 5;
  const int fr = lane & 15;
  const int kg = (lane >> 4) << 3;
  f32x4 acc[4][4] = {};
  const int wr = wave >> 1, wc = wave & 1;

  s16x8 ra[2], rb[2];
  auto load_regs = [&](int kt) {
    const int kk = k0 + (kt << 5) + kg;
#pragma unroll
    for (int i = 0; i < 2; ++i) {
      const int f = i * 4 + wave;
      ra[i] = *(const s16x8*)(A + (size_t)(bm * 128 + f * 16 + fr) * K + kk);
      rb[i] = *(const s16x8*)(B + (size_t)(bn * 128 + f * 16 + fr) * K + kk);
    }
  };
  auto write_lds = [&]() {
#pragma unroll
    for (int i = 0; i < 2; ++i) {
      const int f = i * 4 + wave;
      *(s16x8*)(&lds[0][f][lane][0]) = ra[i];
      *(s16x8*)(&lds[1][f][lane][0]) = rb[i];
    }
  };
  auto compute = [&]() {
    s16x8 af[4], bf[4];
#pragma unroll
    for (int m = 0; m < 4; ++m) af[m] = *(const s16x8*)(&lds[0][wr * 4 + m][lane][0]);
#pragma unroll
    for (int n2 = 0; n2 < 4; ++n2) bf[n2] = *(const s16x8*)(&lds[1][wc * 4 + n2][lane][0]);
#pragma unroll
    for (int m = 0; m < 4; ++m)
#pragma unroll
      for (int n2 = 0; n2 < 4; ++n2) mfma16h(acc[m][n2], af[m], bf[n2]);
  };

  load_regs(0);
  write_lds();
  for (int t = 0; t < nt; ++t) {
    __syncthreads();
    if (t + 1 < nt) load_regs(t + 1);
    compute();
    __syncthreads();
    if (t + 1 < nt) write_lds();
  }

  const int r0 = bm * 128 + wr * 64 + (lane >> 4) * 4;
  const int c0 = bn * 128 + wc * 64 + (lane & 15);
  if constexpr (MODE == 0) {
    u16* C = (u16*)Cout;
#pragma unroll
    for (int m = 0; m < 4; ++m)
#pragma unroll
      for (int n2 = 0; n2 < 4; ++n2)
#pragma unroll
        for (int r = 0; r < 4; ++r)
          C[(size_t)(r0 + m * 16 + r) * N + (c0 + n2 * 16)] = f2h(acc[m][n2][r]);
  } else if constexpr (MODE == 1) {
    float* C = (float*)Cout + (size_t)bz * M * N;
#pragma unroll
    for (int m = 0; m < 4; ++m)
#pragma unroll
      for (int n2 = 0; n2 < 4; ++n2)
#pragma unroll
        for (int r = 0; r < 4; ++r)
          C[(size_t)(r0 + m * 16 + r) * N + (c0 + n2 * 16)] = acc[m][n2][r];
  } else {
    float* C = (float*)Cout;
#pragma unroll
    for (int m = 0; m < 4; ++m)
#pragma unroll
      for (int n2 = 0; n2 < 4; ++n2)
#pragma unroll
        for (int r = 0; r < 4; ++r)
          atomicAdd(&C[(size_t)(r0 + m * 16 + r) * N + (c0 + n2 * 16)],
                    acc[m][n2][r]);
  }
}

// ---------------------------------------------------------------------------
extern "C" void kernel_launch(void* const* d_in, const int* in_sizes, int n_in,
                              void* d_out, int out_size, void* d_ws, size_t ws_size,
                              hipStream_t stream)
{
  const float* tgt  = (const float*)d_in[0];
  const float* mem  = (const float*)d_in[1];
  const float* Wq   = (const float*)d_in[2];
  const float* Wk   = (const float*)d_in[3];
  const float* Wv   = (const float*)d_in[4];
  const float* Wo   = (const float*)d_in[5];
  const float* ln1g = (const float*)d_in[6];
  const float* ln1b = (const float*)d_in[7];
  const float* ln2g = (const float*)d_in[8];
  const float* ln2b = (const float*)d_in[9];
  const float* W1   = (const float*)d_in[10];
  const float* Wd   = (const float*)d_in[11];
  const float* W2   = (const float*)d_in[12];
  const int* ipair  = (const int*)d_in[13];
  const int* kbc    = (const int*)d_in[15];
  const int* ipb    = (const int*)d_in[16];
  float* out = (float*)d_out;

  char* p = (char*)d_ws;
  auto alloc = [&](size_t bytes) {
    char* r = p;
    p += (bytes + 255) & ~(size_t)255;
    return (void*)r;
  };
  u16* tgtT  = (u16*)alloc((size_t)6144 * 128 * 2);    // [(n*3+c)][128] fp16
  u16* memT  = (u16*)alloc((size_t)12288 * 128 * 2);   // [(m*3+c)][128] fp16
  u16* WqH   = (u16*)alloc((size_t)128 * 128 * 2);
  u16* WkvH  = (u16*)alloc((size_t)256 * 128 * 2);     // rows 0-127 Wk, 128-255 Wv
  u16* WoH   = (u16*)alloc((size_t)128 * 128 * 2);
  u16* qT    = (u16*)alloc((size_t)6144 * 128 * 2);    // q-GEMM out
  u16* kvT   = (u16*)alloc((size_t)12288 * 256 * 2);   // kv-GEMM out (K|V)
  u16* aoutT = (u16*)alloc((size_t)6144 * 128 * 2);    // attn out
  float* tgt2T = (float*)alloc((size_t)6144 * 128 * 4);// Wo-GEMM out fp32
  float* h1f  = (float*)alloc((size_t)6144 * 128 * 4); // [(n*3+c)][128] fp32
  u16* h1h  = (u16*)alloc((size_t)6144 * 128 * 2);     // fp16 plane
  u16* W1h  = (u16*)alloc((size_t)DFF * 128 * 2);
  u16* Wdh  = (u16*)alloc((size_t)DFF * DFF * 2);
  u16* W2h  = (u16*)alloc((size_t)128 * DFF * 2);
  u16* Ff16 = (u16*)alloc((size_t)6144 * DFF * 2);     // W1 out
  u16* Dm   = (u16*)alloc((size_t)6144 * DFF * 2);     // Wd out
  u16* Fp   = (u16*)alloc((size_t)6144 * DFF * 2);     // vnrelu out
  float* Gp = (float*)alloc((size_t)6144 * 128 * 4);   // W2 atomic accumulator
  int* dflag = (int*)alloc(256);

  prep_kernel<<<4864, 256, 0, stream>>>(
      tgt, tgtT, mem, memT,
      W1, W1h, DFF * 128, Wd, Wdh, DFF * DFF, W2, W2h, 128 * DFF,
      Wq, WqH, 128 * 128, Wk, WkvH, 128 * 128, Wv, WkvH + 128 * 128, 128 * 128,
      Wo, WoH, 128 * 128, ipair, dflag, Gp);

  // qT = tgtT * Wq^T   (M=6144, N=128, K=128)
  gemm_f16<0><<<dim3(48, 1, 1), 256, 0, stream>>>(tgtT, WqH, qT, 6144, 128, 128);
  // kvT = memT * [Wk;Wv]^T  (M=12288, N=256, K=128)
  gemm_f16<0><<<dim3(96, 2, 1), 256, 0, stream>>>(memT, WkvH, kvT, 12288, 256, 128);
  attn_kernel<<<NQ, 512, 0, stream>>>(qT, kvT, ipair, kbc, ipb, dflag, aoutT);
  // tgt2T = aoutT * Wo^T  (M=6144, N=128, K=128), fp32 out
  gemm_f16<1><<<dim3(48, 1, 1), 256, 0, stream>>>(aoutT, WoH, tgt2T, 6144, 128, 128);
  ln1_kernel<<<NQ, 128, 0, stream>>>(tgt, tgt2T, ln1g, ln1b, h1f, h1h);

  // F = h1 * W1^T   (M=6144, N=2048, K=128), fp16, 128^2 structure
  gemm_f16<0><<<dim3(48, 16, 1), 256, 0, stream>>>(h1h, W1h, Ff16, 6144, DFF, 128);
  // D = F * Wd^T    (M=6144, N=2048, K=2048), fp16, 256^2 phase-scheduled
  gemm_f16_256<<<dim3(24, 8, 1), 512, 0, stream>>>(Ff16, Wdh, Dm, 6144, DFF, DFF);
  // F' = vnrelu(F, D) -> Fp, out-of-place, x8 vectorized
  vnrelu8_kernel<<<(NQ * DFF) / (256 * 8), 256, 0, stream>>>(Ff16, Dm, Fp);
  // Gp += F' * W2^T  (M=6144, N=128, K=2048), split-K=8, fp32 atomic accumulate
  gemm_f16<2><<<dim3(48, 1, SPLITS), 256, 0, stream>>>(Fp, W2h, Gp, 6144, 128, DFF);
  ln2_kernel<<<NQ, 128, 0, stream>>>(h1f, Gp, ln2g, ln2b, out);
}

// Round 21
// 172.681 us; speedup vs baseline: 1.0603x; 1.0603x over previous
//
#include <hip/hip_runtime.h>
#include <stdint.h>

// Problem constants (fixed by the reference)
#define NQ 2048
#define NK 4096
#define DFF 2048
#define SPLITS 4

using u16 = unsigned short;
typedef float f32x4 __attribute__((ext_vector_type(4)));
typedef short s16x8 __attribute__((ext_vector_type(8)));
typedef __attribute__((address_space(3))) void as3_void;
typedef __attribute__((address_space(1))) void as1_void;

__device__ __forceinline__ u16 f2h(float f) {           // fp32 -> fp16 bits (RNE)
  _Float16 h = (_Float16)f;
  return __builtin_bit_cast(u16, h);
}
__device__ __forceinline__ float h2f(u16 u) {
  return (float)__builtin_bit_cast(_Float16, u);
}
__device__ __forceinline__ void mfma16h(f32x4& d, s16x8 a, s16x8 b) {  // fp16
  asm volatile("v_mfma_f32_16x16x32_f16 %0, %1, %2, %0" : "+v"(d) : "v"(a), "v"(b));
}
// async global->LDS DMA, 16B/lane; LDS dest = wave-uniform base + lane*16.
__device__ __forceinline__ void gll16(const void* g, const void* l) {
  uint32_t off = (uint32_t)(uintptr_t)l;
  off = (uint32_t)__builtin_amdgcn_readfirstlane((int)off);
  __builtin_amdgcn_global_load_lds((const as1_void*)(uintptr_t)g,
                                   (as3_void*)(uintptr_t)off, 16, 0, 0);
}

// ---------------------------------------------------------------------------
// PREP: transpose+quantize tgt/mem (blocks 0..3071) + quantize all 7 weights
// (blocks 3072..4095) + int64-detect.
// ---------------------------------------------------------------------------
__global__ __launch_bounds__(256) void prep_kernel(
    const float* __restrict__ TGT, u16* __restrict__ OT,
    const float* __restrict__ MEM, u16* __restrict__ OM,
    const float* __restrict__ S1, u16* __restrict__ H1, int n1,   // W1
    const float* __restrict__ S2, u16* __restrict__ H2, int n2,   // Wd
    const float* __restrict__ S3, u16* __restrict__ H3, int n3,   // W2
    const float* __restrict__ S4, u16* __restrict__ H4, int n4,   // Wq
    const float* __restrict__ S5, u16* __restrict__ H5, int n5,   // Wk
    const float* __restrict__ S6, u16* __restrict__ H6, int n6,   // Wv
    const float* __restrict__ S7, u16* __restrict__ H7, int n7,   // Wo
    const int* __restrict__ IP, int* __restrict__ flag)
{
  const int bx = blockIdx.x;
  if (bx < 3072) {
    // transpose+quantize: fp32 [n][i*3+c] -> fp16 [(n*3+c)][i]
    const float* X = (bx < 1024) ? TGT : MEM;
    u16* O = (bx < 1024) ? OT : OM;
    const int n0 = ((bx < 1024) ? bx : bx - 1024) * 2;
    for (int e = threadIdx.x; e < 768; e += 256) {
      const int nl = (e >= 384);
      const int r = e - nl * 384;           // c*128 + i
      const int c = r >> 7, i = r & 127;
      O[(size_t)(n0 + nl) * 384 + r] = f2h(X[(size_t)(n0 + nl) * 384 + i * 3 + c]);
    }
    return;
  }
  const int qbx = bx - 3072;                // 1024 quant blocks
  if (qbx == 0 && threadIdx.x == 0) {
    int f = 1;
    for (int j = 1; j < 128; j += 2) f &= (IP[j] == 0);
    *flag = f;
  }
  const int q1 = n1 >> 2, q2 = n2 >> 2, q3 = n3 >> 2, q4 = n4 >> 2;
  const int q5 = n5 >> 2, q6 = n6 >> 2, q7 = n7 >> 2;
  const int e1 = q1, e2 = e1 + q2, e3 = e2 + q3, e4 = e3 + q4;
  const int e5 = e4 + q5, e6 = e5 + q6, e7 = e6 + q7;
  int i = qbx * 256 + threadIdx.x;
  const int stride = 1024 * 256;
  for (; i < e7; i += stride) {
    const float* S;
    u16* H;
    int j = i;
    if (j < e1)      { S = S1; H = H1; }
    else if (j < e2) { S = S2; H = H2; j -= e1; }
    else if (j < e3) { S = S3; H = H3; j -= e2; }
    else if (j < e4) { S = S4; H = H4; j -= e3; }
    else if (j < e5) { S = S5; H = H5; j -= e4; }
    else if (j < e6) { S = S6; H = H6; j -= e5; }
    else             { S = S7; H = H7; j -= e6; }
    float4 v = ((const float4*)S)[j];
    ushort4 o;
    o.x = f2h(v.x); o.y = f2h(v.y); o.z = f2h(v.z); o.w = f2h(v.w);
    ((ushort4*)H)[j] = o;
  }
}

// ---------------------------------------------------------------------------
// Gathered multi-head attention, transposed fp16 operands.
// qT: [(n*3+c)][128] fp16. KV: [(m*3+c)][256] fp16 (cols 0-127 = K, 128-255 = V).
// Output aoutT: [(n*3+c)][128] fp16 (feature index = h*16+d).
// ---------------------------------------------------------------------------
__global__ __launch_bounds__(512) void attn_kernel(
    const u16* __restrict__ qT, const u16* __restrict__ KV,
    const int* __restrict__ IP, const int* __restrict__ KBC,
    const int* __restrict__ IPB, const int* __restrict__ FLAG,
    u16* __restrict__ aoutT)
{
  const int n = blockIdx.x;
  const int t = threadIdx.x;
  const int h = t >> 6, l = t & 63;
  __shared__ float qs[384];             // qs[c*128 + i]
  __shared__ float attn_s[8][64];
  __shared__ int gi_s[8][64];
  if (t < 384) qs[t] = h2f(qT[(size_t)n * 384 + t]);
  const int is64 = *FLAG;
  const long long* IP64 = (const long long*)IP;
  const long long* KBC64 = (const long long*)KBC;
  const long long* IPB64 = (const long long*)IPB;
  const int b = is64 ? (int)IPB64[n] : IPB[n];
  int ks0 = 0;
#pragma unroll
  for (int j = 0; j < 4; ++j) {
    int cnt = is64 ? (int)KBC64[j] : KBC[j];
    ks0 += (j < b) ? cnt : 0;  // exclusive cumsum
  }
  const int ip = is64 ? (int)IP64[(size_t)n * 64 + l] : IP[(size_t)n * 64 + l];
  const bool valid = ip >= 0;
  const int gi = ks0 + (valid ? ip : 0);
  __syncthreads();
  // scores: sum over c (3) x d (16): K at KV[gi*768 + c*256 + h*16 + d]
  const u16* kb = KV + (size_t)gi * 768 + h * 16;
  float s = 0.f;
#pragma unroll
  for (int c = 0; c < 3; ++c) {
    s16x8 k0 = *(const s16x8*)(kb + c * 256);
    s16x8 k1 = *(const s16x8*)(kb + c * 256 + 8);
#pragma unroll
    for (int e = 0; e < 8; ++e) {
      s = fmaf(h2f((u16)k0[e]), qs[c * 128 + h * 16 + e], s);
      s = fmaf(h2f((u16)k1[e]), qs[c * 128 + h * 16 + 8 + e], s);
    }
  }
  s *= 0.25f;  // 1/sqrt(hd)
  if (!valid) s = -1e9f;
  float m = s;
  for (int off = 32; off; off >>= 1) m = fmaxf(m, __shfl_xor(m, off));
  float e = __expf(s - m);
  float sum = e;
  for (int off = 32; off; off >>= 1) sum += __shfl_xor(sum, off);
  attn_s[h][l] = e / sum;
  gi_s[h][l] = gi;
  __syncthreads();
  if (l < 48) {
    const int c = l >> 4, d = l & 15;   // V at KV[gi*768 + c*256 + 128 + h*16+d]
    float acc = 0.f;
#pragma unroll 4
    for (int ll = 0; ll < 64; ++ll)
      acc = fmaf(attn_s[h][ll],
                 h2f(KV[(size_t)gi_s[h][ll] * 768 + c * 256 + 128 + h * 16 + d]), acc);
    aoutT[(size_t)n * 384 + c * 128 + h * 16 + d] = f2h(acc);
  }
}

// ---------------------------------------------------------------------------
// VN LayerNorm 1: h1 = VNLN(x + tgt2). X fp32 [n][i*3+c]; T2T fp32
// [(n*3+c)][128]. Writes fp32 [(n*3+c)][128] AND fp16 plane.
// ---------------------------------------------------------------------------
__global__ __launch_bounds__(128) void ln1_kernel(
    const float* __restrict__ X, const float* __restrict__ T2T,
    const float* __restrict__ G, const float* __restrict__ Bb,
    float* __restrict__ Hf, u16* __restrict__ Hh)
{
  const int n = blockIdx.x, i = threadIdx.x;
  const size_t b0 = (size_t)n * 384 + i * 3;
  const size_t h0 = (size_t)n * 384 + i;  // (n*3+c)*128 + i == n*384 + c*128 + i
  float v0 = X[b0 + 0] + T2T[h0 + 0];
  float v1 = X[b0 + 1] + T2T[h0 + 128];
  float v2 = X[b0 + 2] + T2T[h0 + 256];
  float nn = sqrtf(v0 * v0 + v1 * v1 + v2 * v2 + 1e-6f);
  float s1 = nn, s2 = nn * nn;
  for (int off = 32; off; off >>= 1) { s1 += __shfl_xor(s1, off); s2 += __shfl_xor(s2, off); }
  __shared__ float red[4];
  if ((i & 63) == 0) { red[(i >> 6) * 2] = s1; red[(i >> 6) * 2 + 1] = s2; }
  __syncthreads();
  float mu = (red[0] + red[2]) * (1.0f / 128.0f);
  float ms = (red[1] + red[3]) * (1.0f / 128.0f);
  float var = ms - mu * mu;
  float nnew = (nn - mu) * rsqrtf(var + 1e-5f) * G[i] + Bb[i];
  float sc = nnew / nn;
  float o0 = v0 * sc, o1 = v1 * sc, o2 = v2 * sc;
  Hf[h0 + 0]   = o0;
  Hf[h0 + 128] = o1;
  Hf[h0 + 256] = o2;
  Hh[h0 + 0]   = f2h(o0);
  Hh[h0 + 128] = f2h(o1);
  Hh[h0 + 256] = f2h(o2);
}

// ---------------------------------------------------------------------------
// VN LayerNorm 2: out = VNLN(h1 + sum_z Gpart); fp32 in, fp32 out [n][i*3+c]
// ---------------------------------------------------------------------------
__global__ __launch_bounds__(128) void ln2_kernel(
    const float* __restrict__ Hf, const float* __restrict__ Gp,
    const float* __restrict__ G, const float* __restrict__ Bb, float* __restrict__ O)
{
  const int n = blockIdx.x, i = threadIdx.x;
  float v[3];
#pragma unroll
  for (int c = 0; c < 3; ++c) {
    float s = Hf[(size_t)n * 384 + c * 128 + i];
    const float* gp = Gp + (size_t)(n * 3 + c) * 128 + i;
#pragma unroll
    for (int z = 0; z < SPLITS; ++z) s += gp[(size_t)z * 6144 * 128];
    v[c] = s;
  }
  float nn = sqrtf(v[0] * v[0] + v[1] * v[1] + v[2] * v[2] + 1e-6f);
  float s1 = nn, s2 = nn * nn;
  for (int off = 32; off; off >>= 1) { s1 += __shfl_xor(s1, off); s2 += __shfl_xor(s2, off); }
  __shared__ float red[4];
  if ((i & 63) == 0) { red[(i >> 6) * 2] = s1; red[(i >> 6) * 2 + 1] = s2; }
  __syncthreads();
  float mu = (red[0] + red[2]) * (1.0f / 128.0f);
  float ms = (red[1] + red[3]) * (1.0f / 128.0f);
  float var = ms - mu * mu;
  float nnew = (nn - mu) * rsqrtf(var + 1e-5f) * G[i] + Bb[i];
  float sc = nnew / nn;
  const size_t o0 = (size_t)n * 384 + i * 3;
  O[o0 + 0] = v[0] * sc;
  O[o0 + 1] = v[1] * sc;
  O[o0 + 2] = v[2] * sc;
}

// ---------------------------------------------------------------------------
// VN-ReLU, vectorized x8, fp16, OUT-OF-PLACE (F,D -> P). No RMW anywhere.
// ---------------------------------------------------------------------------
__global__ __launch_bounds__(256) void vnrelu8_kernel(
    const u16* __restrict__ F, const u16* __restrict__ D, u16* __restrict__ P)
{
  const size_t idx = (size_t)blockIdx.x * 256 + threadIdx.x;  // one per 8 elems
  const size_t n = idx >> 8;              // DFF/8 = 256 groups per token
  const size_t oo = (idx & 255) << 3;
  const size_t base = n * 3 * DFF + oo;
  s16x8 f0 = *(const s16x8*)(F + base);
  s16x8 f1 = *(const s16x8*)(F + base + DFF);
  s16x8 f2 = *(const s16x8*)(F + base + 2 * DFF);
  s16x8 d0 = *(const s16x8*)(D + base);
  s16x8 d1 = *(const s16x8*)(D + base + DFF);
  s16x8 d2 = *(const s16x8*)(D + base + 2 * DFF);
  s16x8 r0, r1, r2;
#pragma unroll
  for (int e = 0; e < 8; ++e) {
    float a0 = h2f((u16)f0[e]), a1 = h2f((u16)f1[e]), a2 = h2f((u16)f2[e]);
    float b0 = h2f((u16)d0[e]), b1 = h2f((u16)d1[e]), b2 = h2f((u16)d2[e]);
    float dot = a0 * b0 + a1 * b1 + a2 * b2;
    float r = (dot < 0.0f) ? dot / (b0 * b0 + b1 * b1 + b2 * b2 + 1e-6f) : 0.0f;
    r0[e] = (short)f2h(a0 - r * b0);
    r1[e] = (short)f2h(a1 - r * b1);
    r2[e] = (short)f2h(a2 - r * b2);
  }
  *(s16x8*)(P + base) = r0;
  *(s16x8*)(P + base + DFF) = r1;
  *(s16x8*)(P + base + 2 * DFF) = r2;
}

// ---------------------------------------------------------------------------
// fp16 NT GEMM, phase-scheduled 256x256 tile (proven ~73 us @K=2048).
// BK=32, 8 waves (2Mx4N), per-wave 128x64 out (acc 8x4 frags).
// LDS 3-buffer ring (96 KiB), depth-2 gll16 prefetch. Wd GEMM only.
// ---------------------------------------------------------------------------
__global__ __launch_bounds__(512, 1) void gemm_f16_256(
    const u16* __restrict__ A, const u16* __restrict__ B,
    u16* __restrict__ C, int M, int N, int K)
{
  __shared__ __align__(16) u16 lds[3][2][16][64][8];  // 96 KiB ring
  const int tid = threadIdx.x;
  const int wave = tid >> 6, lane = tid & 63;
  const int bm = blockIdx.x, bn = blockIdx.y;
  const int NT = K >> 5;
  const int fr = lane & 15;          // row within 16-row fragment
  const int kg = (lane >> 4) << 3;   // k sub-offset 0/8/16/24
  const int wm = wave >> 2, wn = wave & 3;   // 2 x 4 wave grid
  f32x4 acc[8][4] = {};

  auto stageA = [&](int buf, int kt) {   // 2 gll16: A-frags {2w, 2w+1}
#pragma unroll
    for (int i = 0; i < 2; ++i) {
      const int f = wave * 2 + i;
      gll16(A + (size_t)(bm * 256 + f * 16 + fr) * K + (kt << 5) + kg,
            &lds[buf][0][f][0][0]);
    }
  };
  auto stageB = [&](int buf, int kt) {   // 2 gll16: B-frags {2w, 2w+1}
#pragma unroll
    for (int i = 0; i < 2; ++i) {
      const int f = wave * 2 + i;
      gll16(B + (size_t)(bn * 256 + f * 16 + fr) * K + (kt << 5) + kg,
            &lds[buf][1][f][0][0]);
    }
  };

  // prologue: tiles 0,1 in flight (8 loads/wave); retire tile 0, publish.
  stageA(0, 0); stageB(0, 0);
  stageA(1, 1); stageB(1, 1);
  asm volatile("s_waitcnt vmcnt(4)" ::: "memory");
  __builtin_amdgcn_s_barrier();
  __builtin_amdgcn_sched_barrier(0);

  s16x8 bf[4];
  for (int t = 0; t < NT; ++t) {
    const int cur = t % 3;
    const int nx2 = (t + 2) % 3;
    // ---- phase 0: a-half 0 + all b; stage A of tile t+2 ----
    s16x8 af[4];
#pragma unroll
    for (int i = 0; i < 4; ++i)
      af[i] = *(const s16x8*)(&lds[cur][0][wm * 8 + i][lane][0]);
#pragma unroll
    for (int j = 0; j < 4; ++j)
      bf[j] = *(const s16x8*)(&lds[cur][1][wn * 4 + j][lane][0]);
    if (t + 2 < NT) stageA(nx2, t + 2);
    __builtin_amdgcn_s_barrier();
    asm volatile("s_waitcnt lgkmcnt(0)" ::: "memory");
    __builtin_amdgcn_sched_barrier(0);
    __builtin_amdgcn_s_setprio(1);
#pragma unroll
    for (int i = 0; i < 4; ++i)
#pragma unroll
      for (int j = 0; j < 4; ++j) mfma16h(acc[i][j], af[i], bf[j]);
    __builtin_amdgcn_s_setprio(0);
    // ---- phase 1: a-half 1, b reused from registers; stage B of t+2 ----
#pragma unroll
    for (int i = 0; i < 4; ++i)
      af[i] = *(const s16x8*)(&lds[cur][0][wm * 8 + 4 + i][lane][0]);
    if (t + 2 < NT) stageB(nx2, t + 2);
    __builtin_amdgcn_s_barrier();
    asm volatile("s_waitcnt lgkmcnt(0)" ::: "memory");
    __builtin_amdgcn_sched_barrier(0);
    __builtin_amdgcn_s_setprio(1);
#pragma unroll
    for (int i = 0; i < 4; ++i)
#pragma unroll
      for (int j = 0; j < 4; ++j) mfma16h(acc[4 + i][j], af[i], bf[j]);
    __builtin_amdgcn_s_setprio(0);
    // ---- tile boundary: tile t+1 must be fully landed & published ----
    if (t + 1 < NT) {
      if (t + 2 < NT) {
        asm volatile("s_waitcnt vmcnt(4)" ::: "memory");  // retire t+1's 4, keep t+2's
      } else {
        asm volatile("s_waitcnt vmcnt(0)" ::: "memory");  // tail: nothing newer
      }
      __builtin_amdgcn_s_barrier();
      __builtin_amdgcn_sched_barrier(0);
    }
  }

  // epilogue: C/D frag layout col = lane&15, row = (lane>>4)*4 + reg
  const int r0 = bm * 256 + wm * 128 + (lane >> 4) * 4;
  const int c0 = bn * 256 + wn * 64 + (lane & 15);
#pragma unroll
  for (int ia = 0; ia < 8; ++ia)
#pragma unroll
    for (int jb = 0; jb < 4; ++jb)
#pragma unroll
      for (int r = 0; r < 4; ++r)
        C[(size_t)(r0 + ia * 16 + r) * N + (c0 + jb * 16)] = f2h(acc[ia][jb][r]);
}

// ---------------------------------------------------------------------------
// fp16 NT GEMM: 128x128 tile, BK=32, 4 waves. Register-staged LDS, 2 barriers
// per K-step (replay-proven dynamics). Used for all small-K GEMMs.
// MODE 0: fp16 C. MODE 1: fp32 partials at (float*)C + bz*M*N (split-K on z).
// ---------------------------------------------------------------------------
template <int MODE>
__global__ __launch_bounds__(256) void gemm_f16(
    const u16* __restrict__ A, const u16* __restrict__ B,
    void* __restrict__ Cout, int M, int N, int K)
{
  __shared__ __align__(16) u16 lds[2][8][64][8];  // 16 KiB: A,B
  const int tid = threadIdx.x;
  const int wave = tid >> 6, lane = tid & 63;
  const int bm = blockIdx.x, bn = blockIdx.y, bz = blockIdx.z;
  const int kChunk = K / (int)gridDim.z;
  const int k0 = bz * kChunk;
  const int nt = kChunk >> 5;
  const int fr = lane & 15;
  const int kg = (lane >> 4) << 3;
  f32x4 acc[4][4] = {};
  const int wr = wave >> 1, wc = wave & 1;

  s16x8 ra[2], rb[2];
  auto load_regs = [&](int kt) {
    const int kk = k0 + (kt << 5) + kg;
#pragma unroll
    for (int i = 0; i < 2; ++i) {
      const int f = i * 4 + wave;
      ra[i] = *(const s16x8*)(A + (size_t)(bm * 128 + f * 16 + fr) * K + kk);
      rb[i] = *(const s16x8*)(B + (size_t)(bn * 128 + f * 16 + fr) * K + kk);
    }
  };
  auto write_lds = [&]() {
#pragma unroll
    for (int i = 0; i < 2; ++i) {
      const int f = i * 4 + wave;
      *(s16x8*)(&lds[0][f][lane][0]) = ra[i];
      *(s16x8*)(&lds[1][f][lane][0]) = rb[i];
    }
  };
  auto compute = [&]() {
    s16x8 af[4], bf[4];
#pragma unroll
    for (int m = 0; m < 4; ++m) af[m] = *(const s16x8*)(&lds[0][wr * 4 + m][lane][0]);
#pragma unroll
    for (int n2 = 0; n2 < 4; ++n2) bf[n2] = *(const s16x8*)(&lds[1][wc * 4 + n2][lane][0]);
#pragma unroll
    for (int m = 0; m < 4; ++m)
#pragma unroll
      for (int n2 = 0; n2 < 4; ++n2) mfma16h(acc[m][n2], af[m], bf[n2]);
  };

  load_regs(0);
  write_lds();
  for (int t = 0; t < nt; ++t) {
    __syncthreads();
    if (t + 1 < nt) load_regs(t + 1);
    compute();
    __syncthreads();
    if (t + 1 < nt) write_lds();
  }

  const int r0 = bm * 128 + wr * 64 + (lane >> 4) * 4;
  const int c0 = bn * 128 + wc * 64 + (lane & 15);
  if constexpr (MODE == 0) {
    u16* C = (u16*)Cout;
#pragma unroll
    for (int m = 0; m < 4; ++m)
#pragma unroll
      for (int n2 = 0; n2 < 4; ++n2)
#pragma unroll
        for (int r = 0; r < 4; ++r)
          C[(size_t)(r0 + m * 16 + r) * N + (c0 + n2 * 16)] = f2h(acc[m][n2][r]);
  } else {
    float* C = (float*)Cout + (size_t)bz * M * N;
#pragma unroll
    for (int m = 0; m < 4; ++m)
#pragma unroll
      for (int n2 = 0; n2 < 4; ++n2)
#pragma unroll
        for (int r = 0; r < 4; ++r)
          C[(size_t)(r0 + m * 16 + r) * N + (c0 + n2 * 16)] = acc[m][n2][r];
  }
}

// ---------------------------------------------------------------------------
extern "C" void kernel_launch(void* const* d_in, const int* in_sizes, int n_in,
                              void* d_out, int out_size, void* d_ws, size_t ws_size,
                              hipStream_t stream)
{
  const float* tgt  = (const float*)d_in[0];
  const float* mem  = (const float*)d_in[1];
  const float* Wq   = (const float*)d_in[2];
  const float* Wk   = (const float*)d_in[3];
  const float* Wv   = (const float*)d_in[4];
  const float* Wo   = (const float*)d_in[5];
  const float* ln1g = (const float*)d_in[6];
  const float* ln1b = (const float*)d_in[7];
  const float* ln2g = (const float*)d_in[8];
  const float* ln2b = (const float*)d_in[9];
  const float* W1   = (const float*)d_in[10];
  const float* Wd   = (const float*)d_in[11];
  const float* W2   = (const float*)d_in[12];
  const int* ipair  = (const int*)d_in[13];
  const int* kbc    = (const int*)d_in[15];
  const int* ipb    = (const int*)d_in[16];
  float* out = (float*)d_out;

  char* p = (char*)d_ws;
  auto alloc = [&](size_t bytes) {
    char* r = p;
    p += (bytes + 255) & ~(size_t)255;
    return (void*)r;
  };
  u16* tgtT  = (u16*)alloc((size_t)6144 * 128 * 2);    // [(n*3+c)][128] fp16
  u16* memT  = (u16*)alloc((size_t)12288 * 128 * 2);   // [(m*3+c)][128] fp16
  u16* WqH   = (u16*)alloc((size_t)128 * 128 * 2);
  u16* WkvH  = (u16*)alloc((size_t)256 * 128 * 2);     // rows 0-127 Wk, 128-255 Wv
  u16* WoH   = (u16*)alloc((size_t)128 * 128 * 2);
  u16* qT    = (u16*)alloc((size_t)6144 * 128 * 2);    // q-GEMM out
  u16* kvT   = (u16*)alloc((size_t)12288 * 256 * 2);   // kv-GEMM out (K|V)
  u16* aoutT = (u16*)alloc((size_t)6144 * 128 * 2);    // attn out
  float* tgt2T = (float*)alloc((size_t)6144 * 128 * 4);// Wo-GEMM out fp32
  float* h1f  = (float*)alloc((size_t)6144 * 128 * 4); // [(n*3+c)][128] fp32
  u16* h1h  = (u16*)alloc((size_t)6144 * 128 * 2);     // fp16 plane
  u16* W1h  = (u16*)alloc((size_t)DFF * 128 * 2);
  u16* Wdh  = (u16*)alloc((size_t)DFF * DFF * 2);
  u16* W2h  = (u16*)alloc((size_t)128 * DFF * 2);
  u16* Ff16 = (u16*)alloc((size_t)6144 * DFF * 2);     // W1 out
  u16* Dm   = (u16*)alloc((size_t)6144 * DFF * 2);     // Wd out
  u16* Fp   = (u16*)alloc((size_t)6144 * DFF * 2);     // vnrelu out
  float* Gp = (float*)Ff16;  // alias: Ff16 (25.2 MB) dead after vnrelu reads it;
                             // W2-gemm reads Fp and writes Gp (12.6 MB) — no overlap.
  int* dflag = (int*)alloc(256);

  prep_kernel<<<4096, 256, 0, stream>>>(
      tgt, tgtT, mem, memT,
      W1, W1h, DFF * 128, Wd, Wdh, DFF * DFF, W2, W2h, 128 * DFF,
      Wq, WqH, 128 * 128, Wk, WkvH, 128 * 128, Wv, WkvH + 128 * 128, 128 * 128,
      Wo, WoH, 128 * 128, ipair, dflag);

  // qT = tgtT * Wq^T   (M=6144, N=128, K=128)
  gemm_f16<0><<<dim3(48, 1, 1), 256, 0, stream>>>(tgtT, WqH, qT, 6144, 128, 128);
  // kvT = memT * [Wk;Wv]^T  (M=12288, N=256, K=128)
  gemm_f16<0><<<dim3(96, 2, 1), 256, 0, stream>>>(memT, WkvH, kvT, 12288, 256, 128);
  attn_kernel<<<NQ, 512, 0, stream>>>(qT, kvT, ipair, kbc, ipb, dflag, aoutT);
  // tgt2T = aoutT * Wo^T  (M=6144, N=128, K=128), fp32 out
  gemm_f16<1><<<dim3(48, 1, 1), 256, 0, stream>>>(aoutT, WoH, tgt2T, 6144, 128, 128);
  ln1_kernel<<<NQ, 128, 0, stream>>>(tgt, tgt2T, ln1g, ln1b, h1f, h1h);

  // F = h1 * W1^T   (M=6144, N=2048, K=128), fp16, 128^2 structure
  gemm_f16<0><<<dim3(48, 16, 1), 256, 0, stream>>>(h1h, W1h, Ff16, 6144, DFF, 128);
  // D = F * Wd^T    (M=6144, N=2048, K=2048), fp16, 256^2 phase-scheduled
  gemm_f16_256<<<dim3(24, 8, 1), 512, 0, stream>>>(Ff16, Wdh, Dm, 6144, DFF, DFF);
  // F' = vnrelu(F, D) -> Fp, out-of-place, x8 vectorized
  vnrelu8_kernel<<<(NQ * DFF) / (256 * 8), 256, 0, stream>>>(Ff16, Dm, Fp);
  // Gp partials = F' * W2^T  (M=6144, N=128, K=2048), split-K=4, fp32 partials
  gemm_f16<1><<<dim3(48, 1, SPLITS), 256, 0, stream>>>(Fp, W2h, Gp, 6144, 128, DFF);
  ln2_kernel<<<NQ, 128, 0, stream>>>(h1f, Gp, ln2g, ln2b, out);
}